// Round 1
// baseline (2161.116 us; speedup 1.0000x reference)
//
#include <hip/hip_runtime.h>
#include <hip/hip_bf16.h>

// GroupedExperts: out[t] = (silu(x@w1[e]^T) * (x@w3[e]^T)) @ w2[e]^T
// E=8, T=16384, D=2048, H=5632; tokens pre-sorted by expert, even split.
//
// Pipeline:
//   1) convert f32->bf16: x, w1, w3 into d_ws
//   2) kernel1: grouped dual-GEMM (gate,up) + fused SwiGLU -> h (bf16, T x H)
//   3) convert w2 -> bf16 (reuses w1's ws region; w1b dead after kernel1)
//   4) kernel2: grouped GEMM h @ w2^T -> out (f32)

typedef __bf16 bf16x8 __attribute__((ext_vector_type(8)));
typedef float f32x4 __attribute__((ext_vector_type(4)));
typedef unsigned short u16x8 __attribute__((ext_vector_type(8)));

constexpr int E = 8;
constexpr int T = 16384;
constexpr int D = 2048;
constexpr int H = 5632;

constexpr int BM = 128, BN = 128, BK = 32;

#define DEV static __device__ __forceinline__

DEV unsigned short f2bf(float f) {
    unsigned u = __builtin_bit_cast(unsigned, f);
    u = (u + 0x7FFFu + ((u >> 16) & 1u)) >> 16;   // RNE
    return (unsigned short)u;
}

DEV void gload16(const void* g, void* l) {
    __builtin_amdgcn_global_load_lds(
        (const __attribute__((address_space(1))) void*)g,
        (__attribute__((address_space(3))) void*)l, 16, 0, 0);
}

DEV f32x4 mfma16(bf16x8 a, bf16x8 b, f32x4 c) {
    return __builtin_amdgcn_mfma_f32_16x16x32_bf16(a, b, c, 0, 0, 0);
}

// ---------------- f32 -> bf16 conversion (memory-bound, 8 elems/thread) ----
__global__ __launch_bounds__(256) void k_cvt(const float* __restrict__ in,
                                             unsigned short* __restrict__ out,
                                             long n8) {
    long i = (long)blockIdx.x * blockDim.x + threadIdx.x;
    long stride = (long)gridDim.x * blockDim.x;
    for (; i < n8; i += stride) {
        const float4* p = (const float4*)(in + i * 8);
        float4 a = p[0], b = p[1];
        u16x8 r;
        r[0] = f2bf(a.x); r[1] = f2bf(a.y); r[2] = f2bf(a.z); r[3] = f2bf(a.w);
        r[4] = f2bf(b.x); r[5] = f2bf(b.y); r[6] = f2bf(b.z); r[7] = f2bf(b.w);
        *(u16x8*)(out + i * 8) = r;
    }
}

// ---------------- expert lookup for a row tile ----------------------------
DEV int expert_of_row(const int* __restrict__ ntp, int row0) {
    int e = 0, s = 0;
    for (int i = 0; i < E; ++i) {
        int c = ntp[i];
        if (row0 < s + c) { e = i; break; }
        s += c;
    }
    return e;
}

// ---------------- kernel 1: gate/up dual grouped GEMM + SwiGLU ------------
// A = xb (T x D bf16, row-major), B1 = w1b[e] (H x D), B3 = w3b[e] (H x D).
// Output h (T x H bf16). 128x128 tile, BK=32, 4 waves (2x2), 16x16x32 MFMA.
__global__ __launch_bounds__(256, 2) void k_gate_up(
    const unsigned short* __restrict__ xb,
    const unsigned short* __restrict__ w1b,
    const unsigned short* __restrict__ w3b,
    const int* __restrict__ ntp,
    unsigned short* __restrict__ hbuf) {
    __shared__ unsigned short sA[2][BM * BK];
    __shared__ unsigned short sB1[2][BN * BK];
    __shared__ unsigned short sB3[2][BN * BK];

    constexpr int nTn = H / BN;  // 44
    const int nwg = gridDim.x;   // 5632, multiple of 8
    const int bid = blockIdx.x;
    const int cpx = nwg >> 3;
    const int swz = (bid & 7) * cpx + (bid >> 3);  // XCD-aware swizzle
    const int tm = swz / nTn, tn = swz % nTn;

    const int row0 = tm * BM;
    const int e = expert_of_row(ntp, row0);

    const int tid = threadIdx.x;
    const int wid = tid >> 6, lane = tid & 63;
    const int wm = wid >> 1, wn = wid & 1;

    // staging: thread t covers tile-linear bytes [t*16, t*16+16):
    // row = t/4, k-offset = (t&3)*8 (rows are BK=32 bf16 = 64B)
    const int srow = tid >> 2;
    const int skoff = (tid & 3) << 3;
    const unsigned short* gA = xb + (size_t)(row0 + srow) * D + skoff;
    const unsigned short* gB1 =
        w1b + (size_t)e * H * D + (size_t)(tn * BN + srow) * D + skoff;
    const unsigned short* gB3 =
        w3b + (size_t)e * H * D + (size_t)(tn * BN + srow) * D + skoff;

    auto stage = [&](int buf, int k0) {
        const unsigned short* a = gA + k0;
        const unsigned short* b1 = gB1 + k0;
        const unsigned short* b3 = gB3 + k0;
        char* lA = (char*)&sA[buf][0] + wid * 1024;
        char* lB1 = (char*)&sB1[buf][0] + wid * 1024;
        char* lB3 = (char*)&sB3[buf][0] + wid * 1024;
        gload16(a, lA);
        gload16(a + 64 * D, lA + 4096);
        gload16(b1, lB1);
        gload16(b1 + 64 * D, lB1 + 4096);
        gload16(b3, lB3);
        gload16(b3 + 64 * D, lB3 + 4096);
    };

    f32x4 accg[4][4] = {};
    f32x4 accu[4][4] = {};

    const int krow = (lane >> 4) << 3;       // k sub-offset: 0,8,16,24
    const int frA = wm * 64 + (lane & 15);   // + mi*16
    const int frB = wn * 64 + (lane & 15);   // + ni*16

    stage(0, 0);
    __syncthreads();

    constexpr int nK = D / BK;  // 64
    int cur = 0;
    for (int kt = 0; kt < nK; ++kt) {
        if (kt + 1 < nK) stage(cur ^ 1, (kt + 1) * BK);

        bf16x8 af[4], b1f[4], b3f[4];
#pragma unroll
        for (int mi = 0; mi < 4; ++mi)
            af[mi] = *(const bf16x8*)&sA[cur][(frA + mi * 16) * BK + krow];
#pragma unroll
        for (int ni = 0; ni < 4; ++ni) {
            b1f[ni] = *(const bf16x8*)&sB1[cur][(frB + ni * 16) * BK + krow];
            b3f[ni] = *(const bf16x8*)&sB3[cur][(frB + ni * 16) * BK + krow];
        }
#pragma unroll
        for (int mi = 0; mi < 4; ++mi)
#pragma unroll
            for (int ni = 0; ni < 4; ++ni) {
                accg[mi][ni] = mfma16(af[mi], b1f[ni], accg[mi][ni]);
                accu[mi][ni] = mfma16(af[mi], b3f[ni], accu[mi][ni]);
            }
        __syncthreads();
        cur ^= 1;
    }

    // Epilogue: SwiGLU, store bf16 h. C/D: col=lane&15, row=(lane>>4)*4+j.
    const int trow0 = row0 + wm * 64 + ((lane >> 4) << 2);
    const int hcol0 = tn * BN + wn * 64 + (lane & 15);
#pragma unroll
    for (int mi = 0; mi < 4; ++mi)
#pragma unroll
        for (int ni = 0; ni < 4; ++ni) {
            f32x4 g = accg[mi][ni], u = accu[mi][ni];
#pragma unroll
            for (int j = 0; j < 4; ++j) {
                float gv = g[j];
                float hv = gv * u[j] / (1.f + __expf(-gv));
                hbuf[(size_t)(trow0 + mi * 16 + j) * H + (hcol0 + ni * 16)] =
                    f2bf(hv);
            }
        }
}

// ---------------- kernel 2: down grouped GEMM -----------------------------
// A = h (T x H bf16), B = w2b[e] (D x H), out (T x D f32). K = H = 5632.
__global__ __launch_bounds__(256, 2) void k_down(
    const unsigned short* __restrict__ hbuf,
    const unsigned short* __restrict__ w2b,
    const int* __restrict__ ntp,
    float* __restrict__ out) {
    __shared__ unsigned short sA[2][BM * BK];
    __shared__ unsigned short sB[2][BN * BK];

    constexpr int nTn = D / BN;  // 16
    const int nwg = gridDim.x;   // 2048, multiple of 8
    const int bid = blockIdx.x;
    const int cpx = nwg >> 3;
    const int swz = (bid & 7) * cpx + (bid >> 3);
    const int tm = swz / nTn, tn = swz % nTn;

    const int row0 = tm * BM;
    const int e = expert_of_row(ntp, row0);

    const int tid = threadIdx.x;
    const int wid = tid >> 6, lane = tid & 63;
    const int wm = wid >> 1, wn = wid & 1;

    const int srow = tid >> 2;
    const int skoff = (tid & 3) << 3;
    const unsigned short* gA = hbuf + (size_t)(row0 + srow) * H + skoff;
    const unsigned short* gB =
        w2b + (size_t)e * D * H + (size_t)(tn * BN + srow) * H + skoff;

    auto stage = [&](int buf, int k0) {
        const unsigned short* a = gA + k0;
        const unsigned short* b = gB + k0;
        char* lA = (char*)&sA[buf][0] + wid * 1024;
        char* lB = (char*)&sB[buf][0] + wid * 1024;
        gload16(a, lA);
        gload16(a + 64 * H, lA + 4096);
        gload16(b, lB);
        gload16(b + 64 * H, lB + 4096);
    };

    f32x4 acc[4][4] = {};

    const int krow = (lane >> 4) << 3;
    const int frA = wm * 64 + (lane & 15);
    const int frB = wn * 64 + (lane & 15);

    stage(0, 0);
    __syncthreads();

    constexpr int nK = H / BK;  // 176
    int cur = 0;
    for (int kt = 0; kt < nK; ++kt) {
        if (kt + 1 < nK) stage(cur ^ 1, (kt + 1) * BK);

        bf16x8 af[4], bf[4];
#pragma unroll
        for (int mi = 0; mi < 4; ++mi)
            af[mi] = *(const bf16x8*)&sA[cur][(frA + mi * 16) * BK + krow];
#pragma unroll
        for (int ni = 0; ni < 4; ++ni)
            bf[ni] = *(const bf16x8*)&sB[cur][(frB + ni * 16) * BK + krow];
#pragma unroll
        for (int mi = 0; mi < 4; ++mi)
#pragma unroll
            for (int ni = 0; ni < 4; ++ni)
                acc[mi][ni] = mfma16(af[mi], bf[ni], acc[mi][ni]);
        __syncthreads();
        cur ^= 1;
    }

    const int trow0 = row0 + wm * 64 + ((lane >> 4) << 2);
    const int dcol0 = tn * BN + wn * 64 + (lane & 15);
#pragma unroll
    for (int mi = 0; mi < 4; ++mi)
#pragma unroll
        for (int ni = 0; ni < 4; ++ni) {
            f32x4 c = acc[mi][ni];
#pragma unroll
            for (int j = 0; j < 4; ++j)
                out[(size_t)(trow0 + mi * 16 + j) * D + (dcol0 + ni * 16)] =
                    c[j];
        }
}

extern "C" void kernel_launch(void* const* d_in, const int* in_sizes, int n_in,
                              void* d_out, int out_size, void* d_ws,
                              size_t ws_size, hipStream_t stream) {
    const float* x = (const float*)d_in[0];
    const float* w1 = (const float*)d_in[1];
    const float* w2 = (const float*)d_in[2];
    const float* w3 = (const float*)d_in[3];
    const int* ntp = (const int*)d_in[4];
    float* out = (float*)d_out;

    char* ws = (char*)d_ws;
    // ws layout (bytes):
    //   xb : [0, 67108864)                    T*D*2
    //   w1b: [67108864, 251658240)            E*H*D*2   (reused for w2b)
    //   w3b: [251658240, 436207616)           E*H*D*2
    //   h  : [436207616, 620756992)           T*H*2
    unsigned short* xb = (unsigned short*)(ws + 0);
    unsigned short* w1b = (unsigned short*)(ws + 67108864L);
    unsigned short* w3b = (unsigned short*)(ws + 251658240L);
    unsigned short* hbuf = (unsigned short*)(ws + 436207616L);
    unsigned short* w2b = w1b;  // dead after kernel1

    const long nx8 = (long)T * D / 8;
    const long nw8 = (long)E * H * D / 8;

    k_cvt<<<2048, 256, 0, stream>>>(x, xb, nx8);
    k_cvt<<<2048, 256, 0, stream>>>(w1, w1b, nw8);
    k_cvt<<<2048, 256, 0, stream>>>(w3, w3b, nw8);

    k_gate_up<<<(T / BM) * (H / BN), 256, 0, stream>>>(xb, w1b, w3b, ntp,
                                                       hbuf);

    k_cvt<<<2048, 256, 0, stream>>>(w2, w2b, nw8);

    k_down<<<(T / BM) * (D / BN), 256, 0, stream>>>(hbuf, w2b, ntp, out);
}

// Round 2
// 1659.314 us; speedup vs baseline: 1.3024x; 1.3024x over previous
//
#include <hip/hip_runtime.h>
#include <hip/hip_bf16.h>

// GroupedExperts: out[t] = (silu(x@w1[e]^T) * (x@w3[e]^T)) @ w2[e]^T
// E=8, T=16384, D=2048, H=5632; tokens pre-sorted by expert, even split.
//
// Round 2: 256x256 tile, BK=32, 8 waves, ring-4 LDS double... quad-buffer,
// counted vmcnt (never 0 in main loop), setprio around MFMA, XOR LDS swizzle
// (linear global_load_lds dest + inverse-swizzled global source).
// gate/up fused as ONE GEMM via 16-row interleaved w13 packing.

typedef __bf16 bf16x8 __attribute__((ext_vector_type(8)));
typedef float f32x4 __attribute__((ext_vector_type(4)));
typedef unsigned short u16x8 __attribute__((ext_vector_type(8)));

constexpr int E = 8;
constexpr int T = 16384;
constexpr int D = 2048;
constexpr int H = 5632;

#define DEV static __device__ __forceinline__

DEV unsigned short f2bf(float f) {
    unsigned u = __builtin_bit_cast(unsigned, f);
    u = (u + 0x7FFFu + ((u >> 16) & 1u)) >> 16;   // RNE
    return (unsigned short)u;
}

DEV void gload16(const void* g, void* l) {
    __builtin_amdgcn_global_load_lds(
        (const __attribute__((address_space(1))) void*)g,
        (__attribute__((address_space(3))) void*)l, 16, 0, 0);
}

DEV f32x4 mfma16(bf16x8 a, bf16x8 b, f32x4 c) {
    return __builtin_amdgcn_mfma_f32_16x16x32_bf16(a, b, c, 0, 0, 0);
}

// ---------------- f32 -> bf16 conversion (linear) -------------------------
__global__ __launch_bounds__(256) void k_cvt(const float* __restrict__ in,
                                             unsigned short* __restrict__ out,
                                             long n8) {
    long i = (long)blockIdx.x * blockDim.x + threadIdx.x;
    long stride = (long)gridDim.x * blockDim.x;
    for (; i < n8; i += stride) {
        const float4* p = (const float4*)(in + i * 8);
        float4 a = p[0], b = p[1];
        u16x8 r;
        r[0] = f2bf(a.x); r[1] = f2bf(a.y); r[2] = f2bf(a.z); r[3] = f2bf(a.w);
        r[4] = f2bf(b.x); r[5] = f2bf(b.y); r[6] = f2bf(b.z); r[7] = f2bf(b.w);
        *(u16x8*)(out + i * 8) = r;
    }
}

// ---------------- f32 -> bf16 with w1/w3 16-row interleave ----------------
// w13b[e] row layout: rows (h>>4)*32 + which*16 + (h&15); which: 0=w1, 1=w3.
__global__ __launch_bounds__(256) void k_cvt_w13(
    const float* __restrict__ in, unsigned short* __restrict__ out,
    int which) {
    const long n8 = (long)E * H * D / 8;
    long i = (long)blockIdx.x * blockDim.x + threadIdx.x;
    long stride = (long)gridDim.x * blockDim.x;
    for (; i < n8; i += stride) {
        int col8 = (int)(i & 255);          // D/8 = 256
        int row = (int)(i >> 8);            // e*H + h
        int e = row / H;
        int h = row - e * H;
        int rr = ((h >> 4) << 5) + (which << 4) + (h & 15);
        const float4* p = (const float4*)(in + i * 8);
        float4 a = p[0], b = p[1];
        u16x8 r;
        r[0] = f2bf(a.x); r[1] = f2bf(a.y); r[2] = f2bf(a.z); r[3] = f2bf(a.w);
        r[4] = f2bf(b.x); r[5] = f2bf(b.y); r[6] = f2bf(b.z); r[7] = f2bf(b.w);
        *(u16x8*)(out + ((size_t)e * (2 * H) + rr) * D + (size_t)col8 * 8) = r;
    }
}

// ---------------- expert lookup for a row tile ----------------------------
DEV int expert_of_row(const int* __restrict__ ntp, int row0) {
    int e = 0, s = 0;
    for (int i = 0; i < E; ++i) {
        int c = ntp[i];
        if (row0 < s + c) { e = i; break; }
        s += c;
    }
    return e;
}

// ---------------- 256x256 BK=32 ring-4 GEMM core --------------------------
// 512 threads = 8 waves (2 M x 4 N). Wave output 128x64 (acc[8][4] f32x4).
// LDS: sA/sB = 4 slots x (256x32) bf16 = 64 KiB each, 128 KiB total.
// Swizzle: 16B k-slot s of row r holds global k-slot s ^ (r&3) ^ ((r>>2)&3).
// Staging: linear global_load_lds dest; global source pre-swizzled.
// Pipeline: stage t+3 while computing t; vmcnt(10) steady (A@top, B@mid);
// 2 MFMA phases of 16 per tile, setprio(1) around each cluster.
template <int LDA, int LDB, int NT>
DEV void gemm_core(const unsigned short* pA,  // per-thread pre-offset
                   const unsigned short* pB,
                   unsigned short* sA, unsigned short* sB, int tid,
                   f32x4 (&acc)[8][4]) {
    const int wid = tid >> 6, lane = tid & 63;
    const int ksl = (((lane >> 4) ^ (lane & 3) ^ ((lane >> 2) & 3)) << 3);
    const int frA = ((wid >> 2) << 7) + (lane & 15);   // wm*128 + (lane&15)
    const int frB = ((wid & 3) << 6) + (lane & 15);    // wn*64  + (lane&15)
    const int aoff = frA * 32 + ksl;
    const int boff = frB * 32 + ksl;
    char* ldsA = (char*)sA + wid * 1024;
    char* ldsB = (char*)sB + wid * 1024;

    auto stageA = [&](int t) {
        const unsigned short* g = pA + t * 32;
        char* l = ldsA + (t & 3) * 16384;
        gload16(g, l);
        gload16(g + (size_t)128 * LDA, l + 8192);
    };
    auto stageB = [&](int t) {
        const unsigned short* g = pB + t * 32;
        char* l = ldsB + (t & 3) * 16384;
        gload16(g, l);
        gload16(g + (size_t)128 * LDB, l + 8192);
    };

    stageA(0); stageB(0);
    stageA(1); stageB(1);
    stageA(2); stageB(2);

    for (int t = 0; t < NT; ++t) {
        const int slot = t & 3;
        if (t + 3 < NT) stageA(t + 3);
        const int rem = NT - 1 - t;
        if (rem >= 3)      asm volatile("s_waitcnt vmcnt(10)" ::: "memory");
        else if (rem == 2) asm volatile("s_waitcnt vmcnt(8)" ::: "memory");
        else if (rem == 1) asm volatile("s_waitcnt vmcnt(4)" ::: "memory");
        else               asm volatile("s_waitcnt vmcnt(0)" ::: "memory");
        __builtin_amdgcn_s_barrier();
        __builtin_amdgcn_sched_barrier(0);  // pin reads after the barrier

        const unsigned short* A = sA + slot * 8192;
        const unsigned short* B = sB + slot * 8192;
        bf16x8 a[4], b[4];
#pragma unroll
        for (int i = 0; i < 4; ++i) a[i] = *(const bf16x8*)&A[aoff + i * 512];
#pragma unroll
        for (int i = 0; i < 4; ++i) b[i] = *(const bf16x8*)&B[boff + i * 512];
        if (t + 3 < NT) stageB(t + 3);
        __builtin_amdgcn_s_setprio(1);
#pragma unroll
        for (int mi = 0; mi < 4; ++mi)
#pragma unroll
            for (int ni = 0; ni < 4; ++ni)
                acc[mi][ni] = mfma16(a[mi], b[ni], acc[mi][ni]);
        __builtin_amdgcn_s_setprio(0);
        __builtin_amdgcn_s_barrier();
#pragma unroll
        for (int i = 0; i < 4; ++i)
            a[i] = *(const bf16x8*)&A[aoff + 2048 + i * 512];
        __builtin_amdgcn_s_setprio(1);
#pragma unroll
        for (int mi = 0; mi < 4; ++mi)
#pragma unroll
            for (int ni = 0; ni < 4; ++ni)
                acc[4 + mi][ni] = mfma16(a[mi], b[ni], acc[4 + mi][ni]);
        __builtin_amdgcn_s_setprio(0);
        __builtin_amdgcn_s_barrier();
    }
}

// ---------------- kernel 1: fused gate/up grouped GEMM + SwiGLU -----------
// A = xb (T x D), B = w13b[e] (2H x D), output h (T x H bf16).
__global__ __launch_bounds__(512, 2) void k_gate_up(
    const unsigned short* __restrict__ xb,
    const unsigned short* __restrict__ w13b,
    const int* __restrict__ ntp,
    unsigned short* __restrict__ hbuf) {
    __shared__ unsigned short sA[4 * 8192];
    __shared__ unsigned short sB[4 * 8192];

    const int nwg = gridDim.x;           // 2816
    const int cpx = nwg >> 3;            // 352
    const int bid = blockIdx.x;
    const int swz = (bid & 7) * cpx + (bid >> 3);
    const int tm = swz & 63;             // tm fastest: B-panel L2 reuse
    const int tn = swz >> 6;             // 0..43

    const int row0 = tm << 8;
    const int e = expert_of_row(ntp, row0);
    const int tid = threadIdx.x;

    // per-thread staging source (inverse-swizzled k-slot)
    const int srow = tid >> 2;
    const int sslot = (tid & 3) ^ ((tid >> 2) & 3) ^ ((tid >> 4) & 3);
    const unsigned short* pA = xb + (size_t)(row0 + srow) * D + sslot * 8;
    const unsigned short* pB = w13b + (size_t)e * (2 * H) * D +
                               (size_t)((tn << 8) + srow) * D + sslot * 8;

    f32x4 acc[8][4] = {};
    gemm_core<D, D, D / 32>(pA, pB, sA, sB, tid, acc);

    // Epilogue: ni pairs (0,1),(2,3) = (gate,up) for h-col blocks.
    const int wid = tid >> 6, lane = tid & 63;
    const int wm = wid >> 2, wn = wid & 3;
    const int rbase = row0 + (wm << 7) + ((lane >> 4) << 2);
    const int cbase = ((tn << 3) + (wn << 1)) << 4;  // (tn*8 + wn*2)*16
#pragma unroll
    for (int mi = 0; mi < 8; ++mi)
#pragma unroll
        for (int pi = 0; pi < 2; ++pi) {
            f32x4 g = acc[mi][2 * pi], u = acc[mi][2 * pi + 1];
            const int hcol = cbase + (pi << 4) + (lane & 15);
#pragma unroll
            for (int j = 0; j < 4; ++j) {
                float gv = g[j];
                float hv = gv * u[j] / (1.f + __expf(-gv));
                hbuf[(size_t)(rbase + (mi << 4) + j) * H + hcol] = f2bf(hv);
            }
        }
}

// ---------------- kernel 2: down grouped GEMM -----------------------------
// A = h (T x H), B = w2b[e] (D x H), out (T x D f32).
__global__ __launch_bounds__(512, 2) void k_down(
    const unsigned short* __restrict__ hbuf,
    const unsigned short* __restrict__ w2b,
    const int* __restrict__ ntp,
    float* __restrict__ out) {
    __shared__ unsigned short sA[4 * 8192];
    __shared__ unsigned short sB[4 * 8192];

    const int nwg = gridDim.x;           // 512
    const int cpx = nwg >> 3;            // 64
    const int bid = blockIdx.x;
    const int swz = (bid & 7) * cpx + (bid >> 3);
    const int tm = swz & 63;
    const int tn = swz >> 6;             // 0..7

    const int row0 = tm << 8;
    const int e = expert_of_row(ntp, row0);
    const int tid = threadIdx.x;

    const int srow = tid >> 2;
    const int sslot = (tid & 3) ^ ((tid >> 2) & 3) ^ ((tid >> 4) & 3);
    const unsigned short* pA = hbuf + (size_t)(row0 + srow) * H + sslot * 8;
    const unsigned short* pB = w2b + (size_t)e * D * H +
                               (size_t)((tn << 8) + srow) * H + sslot * 8;

    f32x4 acc[8][4] = {};
    gemm_core<H, H, H / 32>(pA, pB, sA, sB, tid, acc);

    const int wid = tid >> 6, lane = tid & 63;
    const int wm = wid >> 2, wn = wid & 3;
    const int rbase = row0 + (wm << 7) + ((lane >> 4) << 2);
    const int cb = (tn << 8) + (wn << 6) + (lane & 15);
#pragma unroll
    for (int mi = 0; mi < 8; ++mi)
#pragma unroll
        for (int ni = 0; ni < 4; ++ni) {
            f32x4 c = acc[mi][ni];
#pragma unroll
            for (int j = 0; j < 4; ++j)
                out[(size_t)(rbase + (mi << 4) + j) * D + cb + (ni << 4)] =
                    c[j];
        }
}

extern "C" void kernel_launch(void* const* d_in, const int* in_sizes, int n_in,
                              void* d_out, int out_size, void* d_ws,
                              size_t ws_size, hipStream_t stream) {
    const float* x = (const float*)d_in[0];
    const float* w1 = (const float*)d_in[1];
    const float* w2 = (const float*)d_in[2];
    const float* w3 = (const float*)d_in[3];
    const int* ntp = (const int*)d_in[4];
    float* out = (float*)d_out;

    char* ws = (char*)d_ws;
    // ws layout (bytes):
    //   xb  : [0, 64MiB)                       T*D*2
    //   w13b: [64MiB, 64+352MiB)               E*2H*D*2  (reused for w2b)
    //   h   : [416MiB... exact: 436207616)     T*H*2
    unsigned short* xb = (unsigned short*)(ws + 0);
    unsigned short* w13b = (unsigned short*)(ws + 67108864L);
    unsigned short* hbuf = (unsigned short*)(ws + 67108864L + 385875968L);
    unsigned short* w2b = w13b;  // dead after k_gate_up

    k_cvt<<<2048, 256, 0, stream>>>(x, xb, (long)T * D / 8);
    k_cvt_w13<<<2048, 256, 0, stream>>>(w1, w13b, 0);
    k_cvt_w13<<<2048, 256, 0, stream>>>(w3, w13b, 1);

    k_gate_up<<<(T / 256) * (2 * H / 256), 512, 0, stream>>>(xb, w13b, ntp,
                                                             hbuf);

    k_cvt<<<2048, 256, 0, stream>>>(w2, w2b, (long)E * D * H / 8);

    k_down<<<(T / 256) * (D / 256), 512, 0, stream>>>(hbuf, w2b, ntp, out);
}

// Round 3
// 1476.134 us; speedup vs baseline: 1.4640x; 1.1241x over previous
//
#include <hip/hip_runtime.h>
#include <hip/hip_bf16.h>

// GroupedExperts: out[t] = (silu(x@w1[e]^T) * (x@w3[e]^T)) @ w2[e]^T
// E=8, T=16384, D=2048, H=5632; tokens pre-sorted by expert, even split.
//
// Round 3: m201-style fine-phase schedule. 256x256 tile, BK=64, 8 waves,
// 2-buffer LDS (128 KiB), 4 phases per K-tile, one stage-unit per phase,
// counted vmcnt (4 steady / 2,0 tail), raw s_barrier, setprio around MFMA,
// XOR k-slot swizzle (s' = s ^ (row&7)) with inverse-swizzled global source
// and linear global_load_lds dest. gate/up fused via 16-row w13 interleave.

typedef __bf16 bf16x8 __attribute__((ext_vector_type(8)));
typedef float f32x4 __attribute__((ext_vector_type(4)));
typedef unsigned short u16x8 __attribute__((ext_vector_type(8)));

constexpr int E = 8;
constexpr int T = 16384;
constexpr int D = 2048;
constexpr int H = 5632;

#define DEV static __device__ __forceinline__

DEV unsigned short f2bf(float f) {
    unsigned u = __builtin_bit_cast(unsigned, f);
    u = (u + 0x7FFFu + ((u >> 16) & 1u)) >> 16;   // RNE
    return (unsigned short)u;
}

DEV void gload16(const void* g, void* l) {
    __builtin_amdgcn_global_load_lds(
        (const __attribute__((address_space(1))) void*)g,
        (__attribute__((address_space(3))) void*)l, 16, 0, 0);
}

DEV f32x4 mfma16(bf16x8 a, bf16x8 b, f32x4 c) {
    return __builtin_amdgcn_mfma_f32_16x16x32_bf16(a, b, c, 0, 0, 0);
}

// ---------------- f32 -> bf16 conversion (linear) -------------------------
__global__ __launch_bounds__(256) void k_cvt(const float* __restrict__ in,
                                             unsigned short* __restrict__ out,
                                             long n8) {
    long i = (long)blockIdx.x * blockDim.x + threadIdx.x;
    long stride = (long)gridDim.x * blockDim.x;
    for (; i < n8; i += stride) {
        const float4* p = (const float4*)(in + i * 8);
        float4 a = p[0], b = p[1];
        u16x8 r;
        r[0] = f2bf(a.x); r[1] = f2bf(a.y); r[2] = f2bf(a.z); r[3] = f2bf(a.w);
        r[4] = f2bf(b.x); r[5] = f2bf(b.y); r[6] = f2bf(b.z); r[7] = f2bf(b.w);
        *(u16x8*)(out + i * 8) = r;
    }
}

// ---------------- f32 -> bf16 with w1/w3 16-row interleave ----------------
// w13b[e] row layout: rows (h>>4)*32 + which*16 + (h&15); which: 0=w1, 1=w3.
__global__ __launch_bounds__(256) void k_cvt_w13(
    const float* __restrict__ in, unsigned short* __restrict__ out,
    int which) {
    const long n8 = (long)E * H * D / 8;
    long i = (long)blockIdx.x * blockDim.x + threadIdx.x;
    long stride = (long)gridDim.x * blockDim.x;
    for (; i < n8; i += stride) {
        int col8 = (int)(i & 255);          // D/8 = 256
        int row = (int)(i >> 8);            // e*H + h
        int e = row / H;
        int h = row - e * H;
        int rr = ((h >> 4) << 5) + (which << 4) + (h & 15);
        const float4* p = (const float4*)(in + i * 8);
        float4 a = p[0], b = p[1];
        u16x8 r;
        r[0] = f2bf(a.x); r[1] = f2bf(a.y); r[2] = f2bf(a.z); r[3] = f2bf(a.w);
        r[4] = f2bf(b.x); r[5] = f2bf(b.y); r[6] = f2bf(b.z); r[7] = f2bf(b.w);
        *(u16x8*)(out + ((size_t)e * (2 * H) + rr) * D + (size_t)col8 * 8) = r;
    }
}

// ---------------- expert lookup for a row tile ----------------------------
DEV int expert_of_row(const int* __restrict__ ntp, int row0) {
    int e = 0, s = 0;
    for (int i = 0; i < E; ++i) {
        int c = ntp[i];
        if (row0 < s + c) { e = i; break; }
        s += c;
    }
    return e;
}

// ---------------- 256x256 BK=64 fine-phase GEMM core ----------------------
// 512 thr = 8 waves (2M x 4N); wave out 128x64 = acc[8][4] f32x4.
// LDS: sA,sB = 2 buf x 256 rows x 64 el (128B rows) = 64 KiB each.
// Swizzle: 16B slot s of row r stored at s^(r&7); staging source pre-applies
// the inverse, global_load_lds dest stays linear.
// Stage units (consumption-ordered ring, 1 unit = 2 gloads/wave/phase):
//   A1 = rows {0-63,128-191} (read P0), B1 = rows {q*64+0..31} (read P0),
//   B2 = rows {q*64+32..63} (read P1),  A2 = rows {64-127,192-255} (read P2).
// Steady-state waits: P0/P1/P3 vmcnt(4), P2 none. Tail: vmcnt(2), vmcnt(0).
template <int LD_A, int LD_B, int NT>
DEV void gemm8(const unsigned short* pa, const unsigned short* pb,
               unsigned short* sA, unsigned short* sB, int tid,
               f32x4 (&acc)[8][4]) {
    const int lane = tid & 63, wid = tid >> 6;
    const int wm = wid >> 2, wn = wid & 3;

    // staging dests (wave-uniform base; HW adds lane*16)
    char* lA = (char*)sA;
    char* lB = (char*)sB;
    const int dA = wid << 10;                                  // wid*1024
    const int chunkrow = ((wid >> 2) << 6) + ((wid & 3) << 3); // B row base
    const int dB = chunkrow << 7;                              // *128 bytes

    // LDS read bases (ushort units)
    const int x0 = ((lane >> 4) ^ (lane & 7)) << 3;  // kk=0 slot, elements
    const int x1 = x0 ^ 32;                          // kk=1
    const int arow = ((wm << 7) + (lane & 15)) << 6; // *64 el
    const int brow = ((wn << 6) + (lane & 15)) << 6;

    auto stA1 = [&](int bo) {
        gload16(pa, lA + bo + dA);
        gload16(pa + (size_t)128 * LD_A, lA + bo + dA + 16384);
    };
    auto stA2 = [&](int bo) {
        gload16(pa + (size_t)64 * LD_A, lA + bo + dA + 8192);
        gload16(pa + (size_t)192 * LD_A, lA + bo + dA + 24576);
    };
    auto stB1 = [&](int bo) {
        gload16(pb, lB + bo + dB);
        gload16(pb + (size_t)128 * LD_B, lB + bo + dB + 16384);
    };
    auto stB2 = [&](int bo) {
        gload16(pb + (size_t)32 * LD_B, lB + bo + dB + 4096);
        gload16(pb + (size_t)160 * LD_B, lB + bo + dB + 20480);
    };

    // prologue: tile 0 into buf0
    stA1(0); stB1(0); stB2(0); stA2(0);
    pa += 64; pb += 64;
    asm volatile("s_waitcnt vmcnt(4)" ::: "memory");
    __builtin_amdgcn_s_barrier();

#pragma unroll 1
    for (int kt = 0; kt < NT; ++kt) {
        const int bo = (kt & 1) << 15;   // LDS buffer byte offset
        const int nbo = bo ^ 32768;
        const bool more = (kt + 1 < NT);
        const unsigned short* Ab = sA + (bo >> 1) + arow;
        const unsigned short* Bb = sB + (bo >> 1) + brow;
        bf16x8 aT[4][2], bT[4][2];

        // ===== P0: read A-lo + B-lo; stage A1(next); q(m0-3, n0-1) =====
#pragma unroll
        for (int m = 0; m < 4; ++m) {
            aT[m][0] = *(const bf16x8*)(Ab + m * 1024 + x0);
            aT[m][1] = *(const bf16x8*)(Ab + m * 1024 + x1);
        }
#pragma unroll
        for (int n = 0; n < 2; ++n) {
            bT[n][0] = *(const bf16x8*)(Bb + n * 1024 + x0);
            bT[n][1] = *(const bf16x8*)(Bb + n * 1024 + x1);
        }
        if (more) {
            stA1(nbo);
            asm volatile("s_waitcnt vmcnt(4)" ::: "memory");
        } else {
            asm volatile("s_waitcnt vmcnt(2)" ::: "memory");
        }
        __builtin_amdgcn_s_barrier();
        __builtin_amdgcn_sched_barrier(0);
        __builtin_amdgcn_s_setprio(1);
#pragma unroll
        for (int m = 0; m < 4; ++m)
#pragma unroll
            for (int n = 0; n < 2; ++n) {
                acc[m][n] = mfma16(aT[m][0], bT[n][0], acc[m][n]);
                acc[m][n] = mfma16(aT[m][1], bT[n][1], acc[m][n]);
            }
        __builtin_amdgcn_s_setprio(0);

        // ===== P1: read B-hi; stage B1(next); q(m0-3, n2-3) =====
#pragma unroll
        for (int n = 2; n < 4; ++n) {
            bT[n][0] = *(const bf16x8*)(Bb + n * 1024 + x0);
            bT[n][1] = *(const bf16x8*)(Bb + n * 1024 + x1);
        }
        if (more) {
            stB1(nbo);
            asm volatile("s_waitcnt vmcnt(4)" ::: "memory");
        } else {
            asm volatile("s_waitcnt vmcnt(0)" ::: "memory");
        }
        __builtin_amdgcn_s_barrier();
        __builtin_amdgcn_sched_barrier(0);
        __builtin_amdgcn_s_setprio(1);
#pragma unroll
        for (int m = 0; m < 4; ++m)
#pragma unroll
            for (int n = 2; n < 4; ++n) {
                acc[m][n] = mfma16(aT[m][0], bT[n][0], acc[m][n]);
                acc[m][n] = mfma16(aT[m][1], bT[n][1], acc[m][n]);
            }
        __builtin_amdgcn_s_setprio(0);

        // ===== P2: read A-hi; stage B2(next); q(m4-7, n2-3) =====
#pragma unroll
        for (int m = 0; m < 4; ++m) {
            aT[m][0] = *(const bf16x8*)(Ab + 4096 + m * 1024 + x0);
            aT[m][1] = *(const bf16x8*)(Ab + 4096 + m * 1024 + x1);
        }
        if (more) stB2(nbo);
        __builtin_amdgcn_s_barrier();
        __builtin_amdgcn_sched_barrier(0);
        __builtin_amdgcn_s_setprio(1);
#pragma unroll
        for (int m = 0; m < 4; ++m)
#pragma unroll
            for (int n = 2; n < 4; ++n) {
                acc[4 + m][n] = mfma16(aT[m][0], bT[n][0], acc[4 + m][n]);
                acc[4 + m][n] = mfma16(aT[m][1], bT[n][1], acc[4 + m][n]);
            }
        __builtin_amdgcn_s_setprio(0);

        // ===== P3: no reads; stage A2(next); q(m4-7, n0-1) =====
        if (more) {
            stA2(nbo);
            asm volatile("s_waitcnt vmcnt(4)" ::: "memory");
        }
        __builtin_amdgcn_s_barrier();
        __builtin_amdgcn_sched_barrier(0);
        __builtin_amdgcn_s_setprio(1);
#pragma unroll
        for (int m = 0; m < 4; ++m)
#pragma unroll
            for (int n = 0; n < 2; ++n) {
                acc[4 + m][n] = mfma16(aT[m][0], bT[n][0], acc[4 + m][n]);
                acc[4 + m][n] = mfma16(aT[m][1], bT[n][1], acc[4 + m][n]);
            }
        __builtin_amdgcn_s_setprio(0);

        pa += 64; pb += 64;
    }
}

// ---------------- kernel 1: fused gate/up grouped GEMM + SwiGLU -----------
// A = xb (T x D), B = w13b[e] (2H x D), output h (T x H bf16).
__global__ __launch_bounds__(512, 2) void k_gate_up(
    const unsigned short* __restrict__ xb,
    const unsigned short* __restrict__ w13b,
    const int* __restrict__ ntp,
    unsigned short* __restrict__ hbuf) {
    __shared__ unsigned short sA[2 * 16384];
    __shared__ unsigned short sB[2 * 16384];

    const int nwg = gridDim.x;           // 2816
    const int cpx = nwg >> 3;
    const int bid = blockIdx.x;
    const int swz = (bid & 7) * cpx + (bid >> 3);
    const int tm = swz & 63;             // tm fastest: B-panel L2 reuse
    const int tn = swz >> 6;             // 0..43

    const int row0 = tm << 8;
    const int e = expert_of_row(ntp, row0);
    const int tid = threadIdx.x;
    const int lane = tid & 63, wid = tid >> 6;

    // per-thread staging sources (inverse-swizzled 16B slot)
    const int sr = tid >> 3;                        // A row 0..63
    const int sc = (tid & 7) ^ (sr & 7);
    const unsigned short* pa = xb + (size_t)(row0 + sr) * D + sc * 8;
    const int chunkrow = ((wid >> 2) << 6) + ((wid & 3) << 3);
    const int br = chunkrow + (lane >> 3);
    const int bc = (lane & 7) ^ (lane >> 3);
    const unsigned short* pb = w13b + (size_t)e * (2 * H) * D +
                               (size_t)((tn << 8) + br) * D + bc * 8;

    f32x4 acc[8][4] = {};
    gemm8<D, D, D / 64>(pa, pb, sA, sB, tid, acc);

    // Epilogue: ni pairs (0,1),(2,3) = (gate,up). C/D: col=lane&15,
    // row=(lane>>4)*4+j.
    const int wm = wid >> 2, wn = wid & 3;
    const int rbase = row0 + (wm << 7) + ((lane >> 4) << 2);
    const int cb = (((tn << 3) + (wn << 1)) << 4) + (lane & 15);
#pragma unroll
    for (int mi = 0; mi < 8; ++mi)
#pragma unroll
        for (int pi = 0; pi < 2; ++pi) {
            f32x4 g = acc[mi][2 * pi], u = acc[mi][2 * pi + 1];
            const int hcol = cb + (pi << 4);
#pragma unroll
            for (int j = 0; j < 4; ++j) {
                float gv = g[j];
                float hv = gv * u[j] / (1.f + __expf(-gv));
                hbuf[(size_t)(rbase + (mi << 4) + j) * H + hcol] = f2bf(hv);
            }
        }
}

// ---------------- kernel 2: down grouped GEMM -----------------------------
// A = h (T x H), B = w2b[e] (D x H), out (T x D f32). K = H = 5632.
__global__ __launch_bounds__(512, 2) void k_down(
    const unsigned short* __restrict__ hbuf,
    const unsigned short* __restrict__ w2b,
    const int* __restrict__ ntp,
    float* __restrict__ out) {
    __shared__ unsigned short sA[2 * 16384];
    __shared__ unsigned short sB[2 * 16384];

    const int nwg = gridDim.x;           // 512
    const int cpx = nwg >> 3;
    const int bid = blockIdx.x;
    const int swz = (bid & 7) * cpx + (bid >> 3);
    const int tm = swz & 63;
    const int tn = swz >> 6;             // 0..7

    const int row0 = tm << 8;
    const int e = expert_of_row(ntp, row0);
    const int tid = threadIdx.x;
    const int lane = tid & 63, wid = tid >> 6;

    const int sr = tid >> 3;
    const int sc = (tid & 7) ^ (sr & 7);
    const unsigned short* pa = hbuf + (size_t)(row0 + sr) * H + sc * 8;
    const int chunkrow = ((wid >> 2) << 6) + ((wid & 3) << 3);
    const int br = chunkrow + (lane >> 3);
    const int bc = (lane & 7) ^ (lane >> 3);
    const unsigned short* pb = w2b + (size_t)e * D * H +
                               (size_t)((tn << 8) + br) * H + bc * 8;

    f32x4 acc[8][4] = {};
    gemm8<H, H, H / 64>(pa, pb, sA, sB, tid, acc);

    const int wm = wid >> 2, wn = wid & 3;
    const int rbase = row0 + (wm << 7) + ((lane >> 4) << 2);
    const int cb = (tn << 8) + (wn << 6) + (lane & 15);
#pragma unroll
    for (int mi = 0; mi < 8; ++mi)
#pragma unroll
        for (int ni = 0; ni < 4; ++ni) {
            f32x4 c = acc[mi][ni];
#pragma unroll
            for (int j = 0; j < 4; ++j)
                out[(size_t)(rbase + (mi << 4) + j) * D + cb + (ni << 4)] =
                    c[j];
        }
}

extern "C" void kernel_launch(void* const* d_in, const int* in_sizes, int n_in,
                              void* d_out, int out_size, void* d_ws,
                              size_t ws_size, hipStream_t stream) {
    const float* x = (const float*)d_in[0];
    const float* w1 = (const float*)d_in[1];
    const float* w2 = (const float*)d_in[2];
    const float* w3 = (const float*)d_in[3];
    const int* ntp = (const int*)d_in[4];
    float* out = (float*)d_out;

    char* ws = (char*)d_ws;
    // ws layout (bytes):
    //   xb  : [0, 64MiB)                 T*D*2
    //   w13b: [64MiB, 64+352MiB)         E*2H*D*2  (reused for w2b)
    //   h   : [416MiB, 448MiB)           T*H*2
    unsigned short* xb = (unsigned short*)(ws + 0);
    unsigned short* w13b = (unsigned short*)(ws + 67108864L);
    unsigned short* hbuf = (unsigned short*)(ws + 67108864L + 385875968L);
    unsigned short* w2b = w13b;  // dead after k_gate_up

    k_cvt<<<2048, 256, 0, stream>>>(x, xb, (long)T * D / 8);
    k_cvt_w13<<<2048, 256, 0, stream>>>(w1, w13b, 0);
    k_cvt_w13<<<2048, 256, 0, stream>>>(w3, w13b, 1);

    k_gate_up<<<(T / 256) * (2 * H / 256), 512, 0, stream>>>(xb, w13b, ntp,
                                                             hbuf);

    k_cvt<<<2048, 256, 0, stream>>>(w2, w2b, (long)E * D * H / 8);

    k_down<<<(T / 256) * (D / 256), 512, 0, stream>>>(hbuf, w2b, ntp, out);
}